// Round 3
// baseline (470.433 us; speedup 1.0000x reference)
//
#include <hip/hip_runtime.h>

typedef unsigned int u32;

// Shapes (hardcoded from setup_inputs): B=4, C=32, Cr=16, H=64, W=128, D=48.
// Inputs float32, output float32 (reference output dtype).
// Output: (B, 64, D, H, W) C-order; channels [0,32)=cost_var=((l-r)/2)^2 masked,
// [32,48)=cat_l (masked copy), [48,64)=cat_r (shifted masked copy).
// One thread = 4 consecutive w -> one float4 store at out + tid*4.
__global__ __launch_bounds__(256) void costvol_kernel(
    const float* __restrict__ left, const float* __restrict__ rleft,
    const float* __restrict__ right, const float* __restrict__ rright,
    float* __restrict__ out)
{
    const u32 tid = blockIdx.x * 256u + threadIdx.x;
    const u32 w4 = (tid & 31u) << 2;   // starting w, multiple of 4 (32 threads/row)
    u32 row = tid >> 5;
    const u32 h = row & 63u; row >>= 6;
    const u32 d = row % 48u; row /= 48u;
    const u32 c = row & 63u;           // row = b*64 + c
    const u32 b = row >> 6;

    float o[4];

    if (c < 32u) {
        // cost_var channel c
        const u32 base = ((b * 32u + c) * 64u + h) * 128u;
        const float4 lv = *reinterpret_cast<const float4*>(left + base + w4); // 16B aligned
        const float lf[4] = {lv.x, lv.y, lv.z, lv.w};
        const float* rrow = right + base;
        #pragma unroll
        for (int j = 0; j < 4; ++j) {
            const int w = (int)w4 + j;
            const bool act = (w >= (int)d);
            const int off = act ? (w - (int)d) : 0;   // clamp keeps load in-bounds
            const float t = (lf[j] - rrow[off]) * 0.5f;
            o[j] = act ? (t * t) : 0.0f;
        }
    } else if (c < 48u) {
        // cat_l channel c-32: masked copy of reduce_left
        const u32 base = ((b * 16u + (c - 32u)) * 64u + h) * 128u;
        const float4 v = *reinterpret_cast<const float4*>(rleft + base + w4);
        const float vf[4] = {v.x, v.y, v.z, v.w};
        #pragma unroll
        for (int j = 0; j < 4; ++j) {
            o[j] = ((int)w4 + j >= (int)d) ? vf[j] : 0.0f;
        }
    } else {
        // cat_r channel c-48: shifted masked copy of reduce_right
        const u32 base = ((b * 16u + (c - 48u)) * 64u + h) * 128u;
        const float* rrow = rright + base;
        #pragma unroll
        for (int j = 0; j < 4; ++j) {
            const int w = (int)w4 + j;
            const bool act = (w >= (int)d);
            const int off = act ? (w - (int)d) : 0;
            o[j] = act ? rrow[off] : 0.0f;
        }
    }

    // flat out index == tid*4 by construction; 16B-aligned coalesced store
    float4 ov; ov.x = o[0]; ov.y = o[1]; ov.z = o[2]; ov.w = o[3];
    *reinterpret_cast<float4*>(out + (size_t)tid * 4u) = ov;
}

extern "C" void kernel_launch(void* const* d_in, const int* in_sizes, int n_in,
                              void* d_out, int out_size, void* d_ws, size_t ws_size,
                              hipStream_t stream) {
    const float* left   = (const float*)d_in[0];
    const float* rleft  = (const float*)d_in[1];
    const float* right  = (const float*)d_in[2];
    const float* rright = (const float*)d_in[3];
    float* out = (float*)d_out;
    // total threads = 4 * 64 * 48 * 64 * 32 = 25,165,824 -> 98,304 blocks of 256
    const u32 blocks = (4u * 64u * 48u * 64u * 32u) / 256u;
    costvol_kernel<<<blocks, 256, 0, stream>>>(left, rleft, right, rright, out);
}

// Round 4
// 453.134 us; speedup vs baseline: 1.0382x; 1.0382x over previous
//
#include <hip/hip_runtime.h>

typedef unsigned int u32;

// Shapes (hardcoded from setup_inputs): B=4, C=32, Cr=16, H=64, W=128, D=48.
// Inputs float32, output float32, out shape (B, 64, D, H, W) C-order.
// channels [0,32)=cost_var=((l-r_shift)/2)^2 masked, [32,48)=cat_l, [48,64)=cat_r.
//
// Mapping: one WAVE per output row (b,c,d,h); lane handles w=lane and w=lane+64.
// All global loads AND stores are lane-consecutive -> minimal memory transactions
// (~24 segs/wave vs ~96 in the float4-per-thread variant whose right-reads were
// 16B-strided). Upper half w=lane+64 >= 64 > d_max=47 -> never masked.
__global__ __launch_bounds__(256) void costvol_kernel(
    const float* __restrict__ left, const float* __restrict__ rleft,
    const float* __restrict__ right, const float* __restrict__ rright,
    float* __restrict__ out)
{
    const u32 gtid = blockIdx.x * 256u + threadIdx.x;
    const u32 lane = gtid & 63u;
    const u32 row  = gtid >> 6;        // row = ((b*64 + c)*48 + d)*64 + h
    const u32 h = row & 63u;
    u32 t = row >> 6;                  // (b*64 + c)*48 + d
    const u32 d = t % 48u;
    t /= 48u;                          // b*64 + c
    const u32 c = t & 63u;
    const u32 b = t >> 6;

    const u32 w1 = lane;               // 0..63  (mask needed: w1 may be < d)
    const u32 w2 = lane + 64u;         // 64..127 (always active: d <= 47)

    float o1, o2;
    if (c < 32u) {
        // cost_var channel c: ((l - r)/2)^2
        const u32 base = ((b * 32u + c) * 64u + h) * 128u;
        const float l1 = left[base + w1];
        const float l2 = left[base + w2];
        const bool act1 = (w1 >= d);
        const u32 off1 = act1 ? (w1 - d) : 0u;   // clamp keeps load in-bounds
        const float r1 = right[base + off1];
        const float r2 = right[base + w2 - d];
        const float t1 = (l1 - r1) * 0.5f;
        const float t2 = (l2 - r2) * 0.5f;
        o1 = act1 ? (t1 * t1) : 0.0f;
        o2 = t2 * t2;
    } else if (c < 48u) {
        // cat_l channel c-32: masked copy of reduce_left
        const u32 base = ((b * 16u + (c - 32u)) * 64u + h) * 128u;
        o1 = (w1 >= d) ? rleft[base + w1] : 0.0f;
        o2 = rleft[base + w2];
    } else {
        // cat_r channel c-48: shifted masked copy of reduce_right
        const u32 base = ((b * 16u + (c - 48u)) * 64u + h) * 128u;
        const bool act1 = (w1 >= d);
        const u32 off1 = act1 ? (w1 - d) : 0u;
        o1 = act1 ? rright[base + off1] : 0.0f;
        o2 = rright[base + w2 - d];
    }

    // out flat index: row*128 + w; both stores lane-consecutive (256B/wave each)
    const u32 ob = row * 128u + lane;
    out[ob] = o1;
    out[ob + 64u] = o2;
}

extern "C" void kernel_launch(void* const* d_in, const int* in_sizes, int n_in,
                              void* d_out, int out_size, void* d_ws, size_t ws_size,
                              hipStream_t stream) {
    const float* left   = (const float*)d_in[0];
    const float* rleft  = (const float*)d_in[1];
    const float* right  = (const float*)d_in[2];
    const float* rright = (const float*)d_in[3];
    float* out = (float*)d_out;
    // waves = B*64ch*D*H = 4*64*48*64 = 786,432 -> threads = 50,331,648
    // blocks of 256 -> 196,608 blocks
    const u32 blocks = (4u * 64u * 48u * 64u * 64u) / 256u;
    costvol_kernel<<<blocks, 256, 0, stream>>>(left, rleft, right, rright, out);
}